// Round 15
// baseline (155.465 us; speedup 1.0000x reference)
//
#include <hip/hip_runtime.h>
#include <hip/hip_bf16.h>

#define NORM_EPS 1e-12f
#define D 60
#define RP 64     // padded word-row length (elements) -> 128 B rows, line-aligned
#define L 24

__device__ __forceinline__ float wave_sum(float v) {
    #pragma unroll
    for (int off = 32; off >= 1; off >>= 1)
        v += __shfl_xor(v, off, 64);
    return v;
}

// butterfly within each 32-lane half (halves stay independent)
__device__ __forceinline__ float half_sum(float v) {
    #pragma unroll
    for (int off = 16; off >= 1; off >>= 1)
        v += __shfl_xor(v, off, 64);
    return v;
}

__device__ __forceinline__ void half_sum3(float& a, float& b, float& c) {
    #pragma unroll
    for (int off = 16; off >= 1; off >>= 1) {
        float ta = __shfl_xor(a, off, 64);
        float tb = __shfl_xor(b, off, 64);
        float tc = __shfl_xor(c, off, 64);
        a += ta; b += tb; c += tc;
    }
}

__device__ __forceinline__ int rfl(int x) { return __builtin_amdgcn_readfirstlane(x); }

__device__ __forceinline__ void unpack2(unsigned p, float& lo, float& hi) {
    unsigned a = p << 16;
    unsigned b = p & 0xffff0000u;
    __builtin_memcpy(&lo, &a, 4);
    __builtin_memcpy(&hi, &b, 4);
}

__device__ __forceinline__ unsigned pack_bf16(float a, float b) {
    __hip_bfloat16 lo = __float2bfloat16(a);   // RNE
    __hip_bfloat16 hi = __float2bfloat16(b);
    unsigned short ul, uh;
    __builtin_memcpy(&ul, &lo, 2);
    __builtin_memcpy(&uh, &hi, 2);
    return (unsigned)ul | ((unsigned)uh << 16);
}

// ---------- precompute: L2-normalized bf16 word table (+ zero row at N) ----------
__global__ __launch_bounds__(256) void norm_bf16_tab_kernel(
    const float* __restrict__ emb, __hip_bfloat16* __restrict__ outw, int N)
{
    int row = (int)(blockIdx.x * blockDim.x + threadIdx.x);
    if (row > N) return;

    uint4* dst = (uint4*)(outw + (size_t)row * RP);
    if (row == N) {  // zero row: masked slots gather here
        uint4 z = make_uint4(0u, 0u, 0u, 0u);
        #pragma unroll
        for (int j = 0; j < 8; ++j) dst[j] = z;
        return;
    }

    const float4* src = (const float4*)(emb + (size_t)row * D);
    float4 v[15];
    #pragma unroll
    for (int i = 0; i < 15; ++i) v[i] = src[i];

    float ss = 0.f;
    #pragma unroll
    for (int i = 0; i < 15; ++i)
        ss += v[i].x * v[i].x + v[i].y * v[i].y + v[i].z * v[i].z + v[i].w * v[i].w;
    float inv = 1.f / fmaxf(sqrtf(ss), NORM_EPS);

    float f[60];
    #pragma unroll
    for (int i = 0; i < 15; ++i) {
        f[4*i+0] = v[i].x * inv; f[4*i+1] = v[i].y * inv;
        f[4*i+2] = v[i].z * inv; f[4*i+3] = v[i].w * inv;
    }
    unsigned w[32];
    #pragma unroll
    for (int i = 0; i < 30; ++i) w[i] = pack_bf16(f[2*i], f[2*i+1]);
    w[30] = 0u; w[31] = 0u;

    #pragma unroll
    for (int j = 0; j < 8; ++j)
        dst[j] = make_uint4(w[4*j+0], w[4*j+1], w[4*j+2], w[4*j+3]);
}

// ---------- score: TWO items per wave, packed-dword gathers ----------
__global__ __launch_bounds__(256) void score_pair_kernel(
    const __hip_bfloat16* __restrict__ wt,     // [NW+1][RP] normalized words
    const float* __restrict__ ent_emb,
    const float* __restrict__ rel_emb,
    const float* __restrict__ e_bias,
    const float* __restrict__ r_bias,
    const int* __restrict__ head,
    const int* __restrict__ relation,
    const int* __restrict__ tail,
    const int* __restrict__ head_w,
    const int* __restrict__ rel_w,
    const int* __restrict__ tail_w,
    const int* __restrict__ head_m,
    const int* __restrict__ rel_m,
    const int* __restrict__ tail_m,
    float* __restrict__ out,
    int B, int NW)
{
    int pid  = (int)((blockIdx.x * (unsigned)blockDim.x + threadIdx.x) >> 6);
    int lane = (int)(threadIdx.x & 63u);
    int nPairs = (B + 1) >> 1;
    if (pid >= nPairs) return;

    int bA = rfl(2 * pid);
    int bBr = 2 * pid + 1;
    bool hasB = bBr < B;
    int bB = rfl(hasB ? bBr : bA);          // clamp (duplicate A; lane32 won't write)

    int hl  = lane & 31;                    // position within half-wave
    bool isB = lane >= 32;
    bool act = hl < 30;                     // 30 lanes × 2 dims = 60
    int dd = act ? (2 * hl) : 0;            // f32 element offset within a row

    // ---- uniform indices + biases (scalar pipe) ----
    int hA = head[bA], rA = relation[bA], tA = tail[bA];
    int hB = head[bB], rB = relation[bB], tB = tail[bB];
    float biasA = e_bias[hA] + e_bias[tA] + r_bias[rA];
    float biasB = e_bias[hB] + e_bias[tB] + r_bias[rB];

    // ---- entity rows: float2 (2 dims/lane), issued early ----
    int hh = isB ? hB : hA;
    int rr = isB ? rB : rA;
    int tt = isB ? tB : tA;
    float2 eh = make_float2(0.f, 0.f), er = make_float2(0.f, 0.f), et2 = make_float2(0.f, 0.f);
    if (act) {
        eh  = *(const float2*)(ent_emb + (size_t)hh * D + dd);
        er  = *(const float2*)(rel_emb + (size_t)rr * D + dd);
        et2 = *(const float2*)(ent_emb + (size_t)tt * D + dd);
    }

    // ---- pools: list-by-list, 24 packed-dword gathers per phase ----
    const unsigned* wt32 = (const unsigned*)wt;   // 32 dwords per row
    float poolLo = 0.f, poolHi = 0.f;             // signed pooled sums (tail negated)

    const int* idpA[3] = { head_w + (size_t)bA * L, rel_w + (size_t)bA * L, tail_w + (size_t)bA * L };
    const int* mkpA[3] = { head_m + (size_t)bA * L, rel_m + (size_t)bA * L, tail_m + (size_t)bA * L };
    const int* idpB[3] = { head_w + (size_t)bB * L, rel_w + (size_t)bB * L, tail_w + (size_t)bB * L };
    const int* mkpB[3] = { head_m + (size_t)bB * L, rel_m + (size_t)bB * L, tail_m + (size_t)bB * L };

    #pragma unroll
    for (int s = 0; s < 3; ++s) {
        // sanitize both items' lists (uniform loads -> scalar regs)
        int sA[L], sB[L];
        int cntA = 0, cntB = 0;
        {
            const int4* ipA = (const int4*)idpA[s];
            const int4* mpA = (const int4*)mkpA[s];
            const int4* ipB = (const int4*)idpB[s];
            const int4* mpB = (const int4*)mkpB[s];
            #pragma unroll
            for (int i = 0; i < 6; ++i) {
                int4 ti = ipA[i]; int4 tm = mpA[i];
                sA[4*i+0] = tm.x ? ti.x : NW; cntA += (tm.x ? 1 : 0);
                sA[4*i+1] = tm.y ? ti.y : NW; cntA += (tm.y ? 1 : 0);
                sA[4*i+2] = tm.z ? ti.z : NW; cntA += (tm.z ? 1 : 0);
                sA[4*i+3] = tm.w ? ti.w : NW; cntA += (tm.w ? 1 : 0);
                int4 ui = ipB[i]; int4 um = mpB[i];
                sB[4*i+0] = um.x ? ui.x : NW; cntB += (um.x ? 1 : 0);
                sB[4*i+1] = um.y ? ui.y : NW; cntB += (um.y ? 1 : 0);
                sB[4*i+2] = um.z ? ui.z : NW; cntB += (um.z ? 1 : 0);
                sB[4*i+3] = um.w ? ui.w : NW; cntB += (um.w ? 1 : 0);
            }
        }
        float cinvA = 1.f / (float)(cntA > 0 ? cntA : 1);
        float cinvB = 1.f / (float)(cntB > 0 ? cntB : 1);
        float cinv = isB ? cinvB : cinvA;

        // 24 gathers: lanes 0-31 read item A's row, 32-63 item B's row
        unsigned p[L];
        #pragma unroll
        for (int j = 0; j < L; ++j) {
            int row = isB ? sB[j] : sA[j];          // v_cndmask of two scalars
            p[j] = wt32[(size_t)row * 32 + hl];     // packed bf16 pair (dims 2hl,2hl+1)
        }

        float a0 = 0.f, a1 = 0.f, b0 = 0.f, b1 = 0.f;
        #pragma unroll
        for (int j = 0; j < L; j += 2) {
            float lo0, hi0, lo1, hi1;
            unpack2(p[j], lo0, hi0);
            unpack2(p[j + 1], lo1, hi1);
            a0 += lo0; b0 += hi0;
            a1 += lo1; b1 += hi1;
        }
        float sgn = (s == 2) ? -1.f : 1.f;
        poolLo += sgn * (a0 + a1) * cinv;
        poolHi += sgn * (b0 + b1) * cinv;
    }

    // ---- entity norms: 3 interleaved half-wave butterflies ----
    float sh = eh.x * eh.x + eh.y * eh.y;
    float sr = er.x * er.x + er.y * er.y;
    float st = et2.x * et2.x + et2.y * et2.y;
    half_sum3(sh, sr, st);
    float ih = 1.f / fmaxf(sqrtf(sh), NORM_EPS);
    float ir = 1.f / fmaxf(sqrtf(sr), NORM_EPS);
    float it = 1.f / fmaxf(sqrtf(st), NORM_EPS);

    float combLo = eh.x * ih + er.x * ir - et2.x * it + poolLo;
    float combHi = eh.y * ih + er.y * ir - et2.y * it + poolHi;

    float sq = act ? (combLo * combLo + combHi * combHi) : 0.f;
    float nsc = sqrtf(half_sum(sq));

    float bias = isB ? biasB : biasA;
    float score = -nsc + bias;

    if (hl == 0) {
        if (!isB) out[bA] = score;
        else if (hasB) out[bBr] = score;
    }
}

// ---------- slow fallback (round-0 verified; used only if ws too small) ----------
__device__ __forceinline__ float word_pool_slow(const float* __restrict__ word_emb,
                                                const int* __restrict__ ids,
                                                const int* __restrict__ mask,
                                                int b, int d, bool act)
{
    float acc = 0.f;
    int cnt = 0;
    #pragma unroll
    for (int l = 0; l < L; ++l) {
        int m = mask[b * L + l];
        if (m) {
            int id = ids[b * L + l];
            float v = act ? word_emb[(size_t)id * D + d] : 0.f;
            float n = sqrtf(wave_sum(v * v));
            acc += v / fmaxf(n, NORM_EPS);
            cnt += 1;
        }
    }
    return acc / (float)(cnt > 0 ? cnt : 1);
}

__global__ __launch_bounds__(256) void transe_score_slow_kernel(
    const float* __restrict__ ent_emb, const float* __restrict__ rel_emb,
    const float* __restrict__ word_emb, const float* __restrict__ e_bias,
    const float* __restrict__ r_bias,
    const int* __restrict__ head, const int* __restrict__ relation,
    const int* __restrict__ tail,
    const int* __restrict__ head_w, const int* __restrict__ rel_w,
    const int* __restrict__ tail_w,
    const int* __restrict__ head_m, const int* __restrict__ rel_m,
    const int* __restrict__ tail_m,
    float* __restrict__ out, int B)
{
    int wid = (int)((blockIdx.x * (unsigned)blockDim.x + threadIdx.x) >> 6);
    int lane = (int)(threadIdx.x & 63u);
    if (wid >= B) return;
    int d = lane;
    bool act = d < D;

    int h = head[wid], r = relation[wid], t = tail[wid];

    float vh = act ? ent_emb[(size_t)h * D + d] : 0.f;
    float vr = act ? rel_emb[(size_t)r * D + d] : 0.f;
    float vt = act ? ent_emb[(size_t)t * D + d] : 0.f;
    vh /= fmaxf(sqrtf(wave_sum(vh * vh)), NORM_EPS);
    vr /= fmaxf(sqrtf(wave_sum(vr * vr)), NORM_EPS);
    vt /= fmaxf(sqrtf(wave_sum(vt * vt)), NORM_EPS);

    float ph = word_pool_slow(word_emb, head_w, head_m, wid, d, act);
    float pr = word_pool_slow(word_emb, rel_w,  rel_m,  wid, d, act);
    float pt = word_pool_slow(word_emb, tail_w, tail_m, wid, d, act);

    float comb = (vh + ph) + (vr + pr) - (vt + pt);
    float nsc = sqrtf(wave_sum(comb * comb));
    float score = -nsc + e_bias[h] + e_bias[t] + r_bias[r];
    if (lane == 0) out[wid] = score;
}

extern "C" void kernel_launch(void* const* d_in, const int* in_sizes, int n_in,
                              void* d_out, int out_size, void* d_ws, size_t ws_size,
                              hipStream_t stream) {
    const float* ent_emb  = (const float*)d_in[0];
    const float* rel_emb  = (const float*)d_in[1];
    const float* word_emb = (const float*)d_in[2];
    const float* e_bias   = (const float*)d_in[3];
    const float* r_bias   = (const float*)d_in[4];
    const int*   head     = (const int*)d_in[5];
    const int*   relation = (const int*)d_in[6];
    const int*   tail     = (const int*)d_in[7];
    const int*   head_w   = (const int*)d_in[8];
    const int*   rel_w    = (const int*)d_in[9];
    const int*   tail_w   = (const int*)d_in[10];
    const int*   head_m   = (const int*)d_in[11];
    const int*   rel_m    = (const int*)d_in[12];
    const int*   tail_m   = (const int*)d_in[13];
    float* out = (float*)d_out;

    int B  = in_sizes[5];
    int NW = in_sizes[2] / D;   // 100000

    size_t wt_bytes = (size_t)(NW + 1) * RP * sizeof(__hip_bfloat16);  // ~12.8 MB

    if (ws_size >= wt_bytes) {
        __hip_bfloat16* wt = (__hip_bfloat16*)d_ws;

        norm_bf16_tab_kernel<<<(NW + 1 + 255) / 256, 256, 0, stream>>>(word_emb, wt, NW);

        int nPairs = (B + 1) >> 1;
        int wavesPerBlock = 4;  // 256 threads
        int grid = (nPairs + wavesPerBlock - 1) / wavesPerBlock;
        score_pair_kernel<<<grid, 256, 0, stream>>>(
            wt, ent_emb, rel_emb, e_bias, r_bias,
            head, relation, tail,
            head_w, rel_w, tail_w, head_m, rel_m, tail_m,
            out, B, NW);
    } else {
        int wpb = 256 / 64;
        transe_score_slow_kernel<<<(B + wpb - 1) / wpb, 256, 0, stream>>>(
            ent_emb, rel_emb, word_emb, e_bias, r_bias,
            head, relation, tail,
            head_w, rel_w, tail_w, head_m, rel_m, tail_m, out, B);
    }
}